// Round 1
// baseline (3359.852 us; speedup 1.0000x reference)
//
#include <hip/hip_runtime.h>
#include <hip/hip_bf16.h>

#define NN 100000
#define INC 1024
#define HID 128
#define NE 1600000

typedef float floatx4 __attribute__((ext_vector_type(4)));
typedef __bf16 bf16x8 __attribute__((ext_vector_type(8)));
typedef unsigned short ushort8v __attribute__((ext_vector_type(8)));
typedef unsigned short ushort4v __attribute__((ext_vector_type(4)));

__device__ __forceinline__ unsigned short f2bf(float f) {
    union { float f; unsigned u; } v; v.f = f;
    unsigned r = v.u + 0x7fffu + ((v.u >> 16) & 1u);   // round-to-nearest-even
    return (unsigned short)(r >> 16);
}

// ---- degree / normalization prep ----
__global__ __launch_bounds__(256) void init_deg_k(float* deg) {
    int i = blockIdx.x * 256 + threadIdx.x;
    if (i < NN) deg[i] = 1.0f;                // self-loop
}

__global__ __launch_bounds__(256) void deg_edges_k(const int* __restrict__ col, float* deg) {
    int e = blockIdx.x * 256 + threadIdx.x;
    if (e < NE) atomicAdd(&deg[col[e]], 1.0f);
}

__global__ __launch_bounds__(256) void dinv_k(const float* __restrict__ deg, float* __restrict__ dinv) {
    int i = blockIdx.x * 256 + threadIdx.x;
    if (i < NN) dinv[i] = rsqrtf(deg[i]);
}

// ---- W [K=1024][N=128] fp32  ->  Wt [n][k] bf16 (coalesced writes) ----
__global__ __launch_bounds__(256) void wt_k(const float* __restrict__ W, unsigned short* __restrict__ Wt) {
    int idx = blockIdx.x * 256 + threadIdx.x;   // 131072 total
    int n = idx >> 10, k = idx & 1023;
    Wt[idx] = f2bf(W[k * HID + n]);
}

// ---- GEMM: hp = (x @ W) * dinv[row]; also seeds out with hp (self-loop term) ----
// Block: 256 thr = 4 waves; tile 64(M) x 128(N), BK=32, mfma_f32_16x16x32_bf16
__global__ __launch_bounds__(256) void gemm_hp_k(
    const float* __restrict__ x, const unsigned short* __restrict__ Wt,
    const float* __restrict__ dinv, float* __restrict__ hp, float* __restrict__ out)
{
    __shared__ unsigned short As[64 * 40];    // pad stride 40 elem = 80 B (16B aligned rows)
    __shared__ unsigned short Bs[128 * 40];
    const int tid  = threadIdx.x;
    const int lane = tid & 63;
    const int wave = tid >> 6;
    const int q    = lane >> 4;     // 0..3
    const int l16  = lane & 15;
    const int brow = blockIdx.x * 64;

    floatx4 acc[8];
#pragma unroll
    for (int t = 0; t < 8; ++t) acc[t] = (floatx4){0.f, 0.f, 0.f, 0.f};

    for (int k0 = 0; k0 < INC; k0 += 32) {
        // stage A: 64 rows x 32 k (fp32 -> bf16)
        {
            const int m  = tid >> 3;          // 0..31
            const int kk = (tid & 7) * 4;     // 0..28
#pragma unroll
            for (int h = 0; h < 2; ++h) {
                const int mm = m + h * 32;
                const int g  = brow + mm;
                float4 v = make_float4(0.f, 0.f, 0.f, 0.f);
                if (g < NN) v = *(const float4*)&x[(size_t)g * INC + k0 + kk];
                ushort4v w;
                w.x = f2bf(v.x); w.y = f2bf(v.y); w.z = f2bf(v.z); w.w = f2bf(v.w);
                *(ushort4v*)&As[mm * 40 + kk] = w;
            }
        }
        // stage B: Bt[n][k] 128 x 32, already bf16 in Wt
        {
            const int n  = tid >> 1;          // 0..127
            const int kk = (tid & 1) * 16;    // 0 or 16
            ushort8v a = *(const ushort8v*)&Wt[(size_t)n * INC + k0 + kk];
            ushort8v b = *(const ushort8v*)&Wt[(size_t)n * INC + k0 + kk + 8];
            *(ushort8v*)&Bs[n * 40 + kk]     = a;
            *(ushort8v*)&Bs[n * 40 + kk + 8] = b;
        }
        __syncthreads();

        const bf16x8 af = *(const bf16x8*)&As[(wave * 16 + l16) * 40 + q * 8];
#pragma unroll
        for (int t = 0; t < 8; ++t) {
            const bf16x8 bf = *(const bf16x8*)&Bs[(t * 16 + l16) * 40 + q * 8];
            acc[t] = __builtin_amdgcn_mfma_f32_16x16x32_bf16(af, bf, acc[t], 0, 0, 0);
        }
        __syncthreads();
    }

    // epilogue: C/D map col=lane&15, row=(lane>>4)*4+reg
#pragma unroll
    for (int r = 0; r < 4; ++r) {
        const int row = brow + wave * 16 + q * 4 + r;
        if (row < NN) {
            const float d = dinv[row];
#pragma unroll
            for (int t = 0; t < 8; ++t) {
                const int col = t * 16 + l16;
                const float v = acc[t][r] * d;
                hp[(size_t)row * HID + col]  = v;
                out[(size_t)row * HID + col] = v;
            }
        }
    }
}

// ---- scatter: out[col[e]] += hp[row[e]]  (32 lanes/edge, float4 gather, 4 atomics) ----
__global__ __launch_bounds__(256) void scatter_k(const int* __restrict__ ei,
                                                 const float* __restrict__ hp,
                                                 float* __restrict__ out)
{
    const int tid = threadIdx.x;
    const long long e = (long long)blockIdx.x * 8 + (tid >> 5);
    if (e >= NE) return;
    const int r = ei[e];
    const int c = ei[NE + e];
    const int l = (tid & 31) * 4;
    const float4 v = *(const float4*)&hp[(size_t)r * HID + l];
    float* o = &out[(size_t)c * HID + l];
    atomicAdd(o + 0, v.x);
    atomicAdd(o + 1, v.y);
    atomicAdd(o + 2, v.z);
    atomicAdd(o + 3, v.w);
}

// ---- final scale by dinv[dst] ----
__global__ __launch_bounds__(256) void scale_k(float4* __restrict__ out, const float* __restrict__ dinv) {
    const size_t i = (size_t)blockIdx.x * 256 + threadIdx.x;   // N*32 float4s
    if (i < (size_t)NN * 32) {
        const float d = dinv[i >> 5];
        float4 v = out[i];
        v.x *= d; v.y *= d; v.z *= d; v.w *= d;
        out[i] = v;
    }
}

extern "C" void kernel_launch(void* const* d_in, const int* in_sizes, int n_in,
                              void* d_out, int out_size, void* d_ws, size_t ws_size,
                              hipStream_t stream) {
    const float* x  = (const float*)d_in[0];
    const float* W  = (const float*)d_in[1];
    const int*   ei = (const int*)d_in[2];
    float* out = (float*)d_out;

    // workspace layout
    float* hp   = (float*)d_ws;                                    // 51,200,000 B
    float* deg  = (float*)((char*)d_ws + (size_t)NN * HID * 4);    // 400,000 B
    float* dinv = deg + NN;                                        // 400,000 B
    unsigned short* Wt = (unsigned short*)(dinv + NN);             // 262,144 B

    init_deg_k<<<(NN + 255) / 256, 256, 0, stream>>>(deg);
    deg_edges_k<<<(NE + 255) / 256, 256, 0, stream>>>(ei + NE, deg);
    dinv_k<<<(NN + 255) / 256, 256, 0, stream>>>(deg, dinv);
    wt_k<<<(INC * HID) / 256, 256, 0, stream>>>(W, Wt);
    gemm_hp_k<<<(NN + 63) / 64, 256, 0, stream>>>(x, Wt, dinv, hp, out);
    scatter_k<<<NE / 8, 256, 0, stream>>>(ei, hp, out);
    scale_k<<<(NN * 32 + 255) / 256, 256, 0, stream>>>((float4*)out, dinv);
}

// Round 2
// 908.303 us; speedup vs baseline: 3.6990x; 3.6990x over previous
//
#include <hip/hip_runtime.h>
#include <hip/hip_bf16.h>

#define NN 100000
#define INC 1024
#define HID 128
#define NE 1600000
#define NB ((NN + 255) / 256)   // 391 scan blocks

typedef float floatx4 __attribute__((ext_vector_type(4)));
typedef __bf16 bf16x8 __attribute__((ext_vector_type(8)));
typedef unsigned short ushort8v __attribute__((ext_vector_type(8)));
typedef unsigned short ushort4v __attribute__((ext_vector_type(4)));

__device__ __forceinline__ unsigned short f2bf(float f) {
    union { float f; unsigned u; } v; v.f = f;
    unsigned r = v.u + 0x7fffu + ((v.u >> 16) & 1u);   // round-to-nearest-even
    return (unsigned short)(r >> 16);
}

// ---- zero the degree histogram (ws is poisoned 0xAA every call) ----
__global__ __launch_bounds__(256) void init_cnt_k(int* cnt) {
    int i = blockIdx.x * 256 + threadIdx.x;
    if (i < NN) cnt[i] = 0;
}

// ---- histogram destination degrees (excluding self-loop) ----
__global__ __launch_bounds__(256) void deg_edges_k(const int* __restrict__ col, int* cnt) {
    int e = blockIdx.x * 256 + threadIdx.x;
    if (e < NE) atomicAdd(&cnt[col[e]], 1);
}

// ---- dinv[i] = rsqrt(cnt[i] + 1)  (self-loop included) ----
__global__ __launch_bounds__(256) void dinv_k(const int* __restrict__ cnt, float* __restrict__ dinv) {
    int i = blockIdx.x * 256 + threadIdx.x;
    if (i < NN) dinv[i] = rsqrtf((float)(cnt[i] + 1));
}

// ---- exclusive scan, pass 1: per-block (256-wide) ----
__global__ __launch_bounds__(256) void scan1_k(const int* __restrict__ cnt,
                                               int* __restrict__ excl, int* __restrict__ bsum) {
    __shared__ int sh[256];
    const int t = threadIdx.x, b = blockIdx.x;
    const int idx = b * 256 + t;
    const int v = (idx < NN) ? cnt[idx] : 0;
    sh[t] = v;
    __syncthreads();
#pragma unroll
    for (int off = 1; off < 256; off <<= 1) {
        const int x = sh[t];
        const int y = (t >= off) ? sh[t - off] : 0;
        __syncthreads();
        sh[t] = x + y;
        __syncthreads();
    }
    if (idx < NN) excl[idx] = sh[t] - v;
    if (t == 255) bsum[b] = sh[255];
}

// ---- exclusive scan, pass 2: scan the 391 block sums (single block, 512 thr) ----
__global__ __launch_bounds__(512) void scan2_k(const int* __restrict__ bsum, int* __restrict__ boff) {
    __shared__ int sh[512];
    const int t = threadIdx.x;
    const int v = (t < NB) ? bsum[t] : 0;
    sh[t] = v;
    __syncthreads();
#pragma unroll
    for (int off = 1; off < 512; off <<= 1) {
        const int x = sh[t];
        const int y = (t >= off) ? sh[t - off] : 0;
        __syncthreads();
        sh[t] = x + y;
        __syncthreads();
    }
    if (t < NB) boff[t] = sh[t] - v;
}

// ---- scan pass 3: rowptr = excl + boff; also init cursor; rowptr[NN] = NE ----
__global__ __launch_bounds__(256) void scan3_k(const int* __restrict__ excl, const int* __restrict__ boff,
                                               int* __restrict__ rowptr, int* __restrict__ cursor) {
    const int idx = blockIdx.x * 256 + threadIdx.x;
    if (idx < NN) {
        const int v = excl[idx] + boff[blockIdx.x];
        rowptr[idx] = v;
        cursor[idx] = v;
    }
    if (idx == 0) rowptr[NN] = NE;
}

// ---- bucket edges by destination: ssrc[rowptr[c] ...] = srcs of c ----
__global__ __launch_bounds__(256) void fill_k(const int* __restrict__ ei,
                                              int* cursor, int* __restrict__ ssrc) {
    const int e = blockIdx.x * 256 + threadIdx.x;
    if (e < NE) {
        const int r = ei[e];
        const int c = ei[NE + e];
        const int pos = atomicAdd(&cursor[c], 1);
        ssrc[pos] = r;
    }
}

// ---- W [K=1024][N=128] fp32 -> Wt [n][k] bf16 ----
__global__ __launch_bounds__(256) void wt_k(const float* __restrict__ W, unsigned short* __restrict__ Wt) {
    int idx = blockIdx.x * 256 + threadIdx.x;   // 131072 total
    int n = idx >> 10, k = idx & 1023;
    Wt[idx] = f2bf(W[k * HID + n]);
}

// ---- GEMM: hp = (x @ W) * dinv[row] ----
__global__ __launch_bounds__(256) void gemm_hp_k(
    const float* __restrict__ x, const unsigned short* __restrict__ Wt,
    const float* __restrict__ dinv, float* __restrict__ hp)
{
    __shared__ unsigned short As[64 * 40];
    __shared__ unsigned short Bs[128 * 40];
    const int tid  = threadIdx.x;
    const int lane = tid & 63;
    const int wave = tid >> 6;
    const int q    = lane >> 4;
    const int l16  = lane & 15;
    const int brow = blockIdx.x * 64;

    floatx4 acc[8];
#pragma unroll
    for (int t = 0; t < 8; ++t) acc[t] = (floatx4){0.f, 0.f, 0.f, 0.f};

    for (int k0 = 0; k0 < INC; k0 += 32) {
        {
            const int m  = tid >> 3;
            const int kk = (tid & 7) * 4;
#pragma unroll
            for (int h = 0; h < 2; ++h) {
                const int mm = m + h * 32;
                const int g  = brow + mm;
                float4 v = make_float4(0.f, 0.f, 0.f, 0.f);
                if (g < NN) v = *(const float4*)&x[(size_t)g * INC + k0 + kk];
                ushort4v w;
                w.x = f2bf(v.x); w.y = f2bf(v.y); w.z = f2bf(v.z); w.w = f2bf(v.w);
                *(ushort4v*)&As[mm * 40 + kk] = w;
            }
        }
        {
            const int n  = tid >> 1;
            const int kk = (tid & 1) * 16;
            ushort8v a = *(const ushort8v*)&Wt[(size_t)n * INC + k0 + kk];
            ushort8v b = *(const ushort8v*)&Wt[(size_t)n * INC + k0 + kk + 8];
            *(ushort8v*)&Bs[n * 40 + kk]     = a;
            *(ushort8v*)&Bs[n * 40 + kk + 8] = b;
        }
        __syncthreads();

        const bf16x8 af = *(const bf16x8*)&As[(wave * 16 + l16) * 40 + q * 8];
#pragma unroll
        for (int t = 0; t < 8; ++t) {
            const bf16x8 bf = *(const bf16x8*)&Bs[(t * 16 + l16) * 40 + q * 8];
            acc[t] = __builtin_amdgcn_mfma_f32_16x16x32_bf16(af, bf, acc[t], 0, 0, 0);
        }
        __syncthreads();
    }

#pragma unroll
    for (int r = 0; r < 4; ++r) {
        const int row = brow + wave * 16 + q * 4 + r;
        if (row < NN) {
            const float d = dinv[row];
#pragma unroll
            for (int t = 0; t < 8; ++t) {
                const int col = t * 16 + l16;
                hp[(size_t)row * HID + col] = acc[t][r] * d;
            }
        }
    }
}

// ---- aggregation: one wave per dst; out[d] = dinv[d] * (hp[d] + sum hp[src]) ----
__global__ __launch_bounds__(256) void agg_k(const int* __restrict__ rowptr,
                                             const int* __restrict__ ssrc,
                                             const float* __restrict__ hp,
                                             const float* __restrict__ dinv,
                                             float* __restrict__ out)
{
    const int w = (blockIdx.x * 256 + threadIdx.x) >> 6;   // dst node
    const int lane = threadIdx.x & 63;
    if (w >= NN) return;
    const int s = rowptr[w];
    const int e = rowptr[w + 1];
    const size_t loff = (size_t)lane * 2;

    const float2 self = *(const float2*)&hp[(size_t)w * HID + loff];
    float ax = self.x, ay = self.y;

    for (int i = s; i < e; i += 64) {
        const int rem = e - i;
        const int cnt = rem < 64 ? rem : 64;
        int srcv = 0;
        if (lane < rem) srcv = ssrc[i + lane];
        int j = 0;
        for (; j + 4 <= cnt; j += 4) {
            const int s0 = __shfl(srcv, j + 0);
            const int s1 = __shfl(srcv, j + 1);
            const int s2 = __shfl(srcv, j + 2);
            const int s3 = __shfl(srcv, j + 3);
            const float2 v0 = *(const float2*)&hp[(size_t)s0 * HID + loff];
            const float2 v1 = *(const float2*)&hp[(size_t)s1 * HID + loff];
            const float2 v2 = *(const float2*)&hp[(size_t)s2 * HID + loff];
            const float2 v3 = *(const float2*)&hp[(size_t)s3 * HID + loff];
            ax += v0.x + v1.x + v2.x + v3.x;
            ay += v0.y + v1.y + v2.y + v3.y;
        }
        for (; j < cnt; ++j) {
            const int sj = __shfl(srcv, j);
            const float2 v = *(const float2*)&hp[(size_t)sj * HID + loff];
            ax += v.x;
            ay += v.y;
        }
    }

    const float d = dinv[w];
    float2 r;
    r.x = ax * d;
    r.y = ay * d;
    *(float2*)&out[(size_t)w * HID + loff] = r;
}

extern "C" void kernel_launch(void* const* d_in, const int* in_sizes, int n_in,
                              void* d_out, int out_size, void* d_ws, size_t ws_size,
                              hipStream_t stream) {
    const float* x  = (const float*)d_in[0];
    const float* W  = (const float*)d_in[1];
    const int*   ei = (const int*)d_in[2];
    float* out = (float*)d_out;

    // workspace layout (bytes)
    char* p = (char*)d_ws;
    float* hp      = (float*)p;            p += (size_t)NN * HID * 4;   // 51.2 MB
    int*   cnt     = (int*)p;              p += (size_t)NN * 4;
    int*   rowptr  = (int*)p;              p += (size_t)(NN + 4) * 4;
    int*   cursor  = (int*)p;              p += (size_t)NN * 4;
    int*   excl    = (int*)p;              p += (size_t)NN * 4;
    float* dinv    = (float*)p;            p += (size_t)NN * 4;
    unsigned short* Wt = (unsigned short*)p; p += (size_t)INC * HID * 2;
    int*   bsum    = (int*)p;              p += 512 * 4;
    int*   boff    = (int*)p;              p += 512 * 4;
    int*   ssrc    = (int*)p;              p += (size_t)NE * 4;         // 6.4 MB

    init_cnt_k <<<NB, 256, 0, stream>>>(cnt);
    deg_edges_k<<<(NE + 255) / 256, 256, 0, stream>>>(ei + NE, cnt);
    dinv_k     <<<NB, 256, 0, stream>>>(cnt, dinv);
    scan1_k    <<<NB, 256, 0, stream>>>(cnt, excl, bsum);
    scan2_k    <<<1, 512, 0, stream>>>(bsum, boff);
    scan3_k    <<<NB, 256, 0, stream>>>(excl, boff, rowptr, cursor);
    fill_k     <<<(NE + 255) / 256, 256, 0, stream>>>(ei, cursor, ssrc);
    wt_k       <<<(INC * HID) / 256, 256, 0, stream>>>(W, Wt);
    gemm_hp_k  <<<(NN + 63) / 64, 256, 0, stream>>>(x, Wt, dinv, hp);
    agg_k      <<<(NN * 64 + 255) / 256, 256, 0, stream>>>(rowptr, ssrc, hp, dinv, out);
}